// Round 7
// baseline (232.894 us; speedup 1.0000x reference)
//
#include <hip/hip_runtime.h>
#include <math.h>

// FeatureSpecExtractor: per-(b,f) EMA-normalize over time.
//   s_t = 0.95*s_{t-1} + 0.05*|x_t|;  y_t = x_t / sqrt(s_t)
// spec: (16,1,257,8000) f32, features 0..255 used. out: (16,1,256,8000) f32.
//
// v3: v2's coalesced segment-scan layout, but TWO rows per block processed
// simultaneously. Rationale (r6 post-mortem): kernel is latency/phase-bound,
// not BW-bound (3.3 TB/s eff. vs 6.5 achievable; VALUBusy 15%). Interleaving
// 2 rows doubles loads-in-flight per thread (8 dwordx4) and halves the
// per-byte cost of the barrier-drained scan phases.

#define TLEN   8000
#define SEGLEN 2000
#define NCHUNK 500            // float4 chunks per segment
#define ALPHA  0.95f
#define OMA    0.05f
#define NR     2              // rows per block

// A4 = 0.95^4 and its powers (Kogge-Stone step coefficients)
#define A4_1   0.81450625f    // 0.95^4
#define A4_2   0.66342043f    // 0.95^8
#define A4_4   0.44012667f    // 0.95^16
#define A4_8   0.19371149f    // 0.95^32
#define A4_16  0.03752414f    // 0.95^64
#define A4_32  0.00140806f    // 0.95^128
#define A256   1.98263565e-06f // 0.95^256: wave->wave carry factor
#define LOG2_A4 (-0.29600231f) // 4*log2(0.95)

__global__ __launch_bounds__(512) void fse_kernel(
    const float* __restrict__ spec,
    const float* __restrict__ uns,
    float* __restrict__ out)
{
    const int p    = blockIdx.x;          // 0..2047: rows 2p, 2p+1
    const int tid  = threadIdx.x;
    const int lane = tid & 63;
    const int w    = tid >> 6;            // wave id 0..7
    const bool active = (tid < NCHUNK);

    const float* inrow[NR];
    float*       outrow[NR];
    float        s0[NR];
#pragma unroll
    for (int r = 0; r < NR; ++r) {
        const int bf = p * NR + r;        // consecutive rows: L2-friendly
        const int b  = bf >> 8;
        const int f  = bf & 255;
        inrow[r]  = spec + ((size_t)b * 257 + (size_t)f) * TLEN;
        outrow[r] = out  + ((size_t)bf) * TLEN;
        s0[r]     = uns[f];
    }

    // ---- 8 coalesced float4 loads, all independent / in flight together ----
    float4 xq[NR][4];
#pragma unroll
    for (int r = 0; r < NR; ++r)
#pragma unroll
        for (int k = 0; k < 4; ++k)
            if (active)
                xq[r][k] = *(const float4*)(inrow[r] + k * SEGLEN + tid * 4);

    // ---- local (zero-init) chunk scans ----
    float v[NR][4];
#pragma unroll
    for (int r = 0; r < NR; ++r)
#pragma unroll
        for (int k = 0; k < 4; ++k) {
            float d = 0.0f;
            if (active) {
                d = fmaf(fabsf(xq[r][k].x), OMA, d * ALPHA);
                d = fmaf(fabsf(xq[r][k].y), OMA, d * ALPHA);
                d = fmaf(fabsf(xq[r][k].z), OMA, d * ALPHA);
                d = fmaf(fabsf(xq[r][k].w), OMA, d * ALPHA);
            }
            v[r][k] = d;
        }

    // ---- 8 interleaved weighted Kogge-Stone scans across the wave ----
#define SCAN_STEP(D, C)                                                  \
    {                                                                    \
        float t[NR][4];                                                  \
        _Pragma("unroll") for (int r = 0; r < NR; ++r)                   \
            _Pragma("unroll") for (int k = 0; k < 4; ++k)                \
                t[r][k] = __shfl_up(v[r][k], D);                         \
        if (lane >= D) {                                                 \
            _Pragma("unroll") for (int r = 0; r < NR; ++r)               \
                _Pragma("unroll") for (int k = 0; k < 4; ++k)            \
                    v[r][k] = fmaf(C, t[r][k], v[r][k]);                 \
        }                                                                \
    }
    SCAN_STEP(1,  A4_1)
    SCAN_STEP(2,  A4_2)
    SCAN_STEP(4,  A4_4)
    SCAN_STEP(8,  A4_8)
    SCAN_STEP(16, A4_16)
    SCAN_STEP(32, A4_32)
#undef SCAN_STEP

    // ---- cross-wave carries (per row, per segment) ----
    __shared__ float tot[NR][4][8];
    __shared__ float segend[NR][4];
    if (lane == 63) {
#pragma unroll
        for (int r = 0; r < NR; ++r)
#pragma unroll
            for (int k = 0; k < 4; ++k) tot[r][k][w] = v[r][k];
    }
    __syncthreads();

    const float pl = exp2f(LOG2_A4 * (float)lane);   // A4^lane
    float e[NR][4];
#pragma unroll
    for (int r = 0; r < NR; ++r)
#pragma unroll
        for (int k = 0; k < 4; ++k) {
            float carry = 0.0f;                      // incl. at end of wave w-1
            for (int j = 0; j < w; ++j) carry = fmaf(carry, A256, tot[r][k][j]);
            float ex = __shfl_up(v[r][k], 1);
            if (lane == 0) ex = 0.0f;
            e[r][k] = fmaf(pl, carry, ex);           // global exclusive (data part)
            if (tid == NCHUNK - 1 && k < 3)          // seg-end inclusive -> seed
                segend[r][k] = fmaf(pl * A4_1, carry, v[r][k]);
        }
    __syncthreads();

    // ---- incoming states, exact 4-step recurrence, coalesced stores ----
    const float pt = exp2f(LOG2_A4 * (float)tid);    // A4^tid (underflow->0 ok)
#pragma unroll
    for (int r = 0; r < NR; ++r) {
        float S0[4];
        S0[0] = s0[r];
        S0[1] = segend[r][0];
        S0[2] = segend[r][1];
        S0[3] = segend[r][2];   // 0.95^2000*S0 underflows: seed = segend exactly
#pragma unroll
        for (int k = 0; k < 4; ++k) {
            if (active) {
                float s = fmaf(pt, S0[k], e[r][k]);
                float4 q = xq[r][k];
                s = fmaf(fabsf(q.x), OMA, s * ALPHA); q.x = q.x * rsqrtf(s);
                s = fmaf(fabsf(q.y), OMA, s * ALPHA); q.y = q.y * rsqrtf(s);
                s = fmaf(fabsf(q.z), OMA, s * ALPHA); q.z = q.z * rsqrtf(s);
                s = fmaf(fabsf(q.w), OMA, s * ALPHA); q.w = q.w * rsqrtf(s);
                *(float4*)(outrow[r] + k * SEGLEN + tid * 4) = q;
            }
        }
    }
}

extern "C" void kernel_launch(void* const* d_in, const int* in_sizes, int n_in,
                              void* d_out, int out_size, void* d_ws, size_t ws_size,
                              hipStream_t stream) {
    const float* spec = (const float*)d_in[0];
    const float* uns  = (const float*)d_in[1];
    float* out = (float*)d_out;
    (void)in_sizes; (void)n_in; (void)d_ws; (void)ws_size; (void)out_size;

    dim3 grid(16 * 256 / NR);   // one block per NR consecutive (b,f) rows
    dim3 block(512);
    fse_kernel<<<grid, block, 0, stream>>>(spec, uns, out);
}